// Round 2
// baseline (467.772 us; speedup 1.0000x reference)
//
#include <hip/hip_runtime.h>
#include <stdint.h>

#define S_LEN 2048
#define HID 3584
#define NHEADS 28
#define NKVH 4
#define DHEAD 128

typedef __attribute__((ext_vector_type(8))) short short8;
typedef __attribute__((ext_vector_type(4))) float f32x4;

__device__ __forceinline__ uint16_t f2bf(float f) {
    uint32_t u = __float_as_uint(f);
    u += 0x7fffu + ((u >> 16) & 1u);   // RNE
    return (uint16_t)(u >> 16);
}

// async global->LDS DMA, 16B per lane; LDS dest = wave-uniform base + lane*16
__device__ __forceinline__ void gload16(const uint16_t* g, uint16_t* l) {
    __builtin_amdgcn_global_load_lds(
        (const __attribute__((address_space(1))) uint32_t*)g,
        (__attribute__((address_space(3))) uint32_t*)l, 16, 0, 0);
}

// ---------------- fused fp32 -> bf16 conversion (all 5 tensors, 1 launch) ----------------
#define C_HS 1835008
#define C_WQ 5046272
#define C_WK 5505024
#define C_WV 5963776
#define C_TOT 9175040
__global__ void cvt_all(const float* __restrict__ hs, const float* __restrict__ Wq,
                        const float* __restrict__ Wk, const float* __restrict__ Wv,
                        const float* __restrict__ Wo,
                        uint16_t* __restrict__ hs_bf, uint16_t* __restrict__ wqkv_bf,
                        uint16_t* __restrict__ wo_bf) {
    int i = blockIdx.x * 256 + threadIdx.x;
    if (i >= C_TOT) return;
    const float* src; uint16_t* dst; int off;
    if (i < C_HS)      { src = hs; dst = hs_bf;               off = i; }
    else if (i < C_WQ) { src = Wq; dst = wqkv_bf;             off = i - C_HS; }
    else if (i < C_WK) { src = Wk; dst = wqkv_bf + 12845056;  off = i - C_WQ; }
    else if (i < C_WV) { src = Wv; dst = wqkv_bf + 14680064;  off = i - C_WK; }
    else               { src = Wo; dst = wo_bf;               off = i - C_WV; }
    float4 f = ((const float4*)src)[off];
    uint2 v;
    v.x = (uint32_t)f2bf(f.x) | ((uint32_t)f2bf(f.y) << 16);
    v.y = (uint32_t)f2bf(f.z) | ((uint32_t)f2bf(f.w) << 16);
    *(uint2*)(dst + (size_t)off * 4) = v;
}

__global__ void concat_bias(const float* __restrict__ bq, const float* __restrict__ bk,
                            const float* __restrict__ bv, float* __restrict__ dst) {
    int i = blockIdx.x * 256 + threadIdx.x;
    if (i < 3584) dst[i] = bq[i];
    else if (i < 4096) dst[i] = bk[i - 3584];
    else if (i < 4608) dst[i] = bv[i - 4096];
}

// ---------------- bf16 GEMM: C = A * B^T (+bias) ----------------
// 256x256 tile, BK=64, 8 waves / 512 threads, 128 KiB LDS.
// 8-phase (4 phases per K-tile, 2 K-tiles per dbuf cycle) schedule with
// COUNTED vmcnt (never 0 in steady state) + s_setprio around MFMA clusters
// (T3+T4+T5). Granule-XOR swizzle (g ^ (row&7)) on 64-col rows keeps
// ds_read_b128 conflict-free (measured 0 conflicts in the 128^2 version).
//
// Phase p computes C-quadrant (mh,nh) in order (0,0),(0,1),(1,0),(1,1).
// LDS half h of A is read only in phase with mh==h's FIRST occurrence
// (A0 @P1, A1 @P3); B halves read once each (B0 @P1, B1 @P2) and both
// held in registers. Stage stream per tile: [A0,B0,B1,A1]; issue schedule
// P1:A1(t+1), P2:A0(t+2), P3:B0(t+2), P4:B1(t+2) -- every DMA into a
// region is issued at least one end-barrier after that region's last
// LDS read (WAR-safe with 2 buffers). vmcnt(6)=3 half-tiles in flight at
// each tile boundary; vmcnt(0) only for the last two tiles.
template <bool OUT_F32>
__global__ __launch_bounds__(512, 2) void gemm_bt256(const uint16_t* __restrict__ A,
                                                     const uint16_t* __restrict__ B,
                                                     const float* __restrict__ bias,
                                                     void* __restrict__ C,
                                                     int N, int K, int ldc)
{
    __shared__ __align__(16) uint16_t As[4 * 8192];   // [buf][half][128*64] = 64 KB
    __shared__ __align__(16) uint16_t Bs[4 * 8192];   // 64 KB
    const int tid  = threadIdx.x;
    const int lane = tid & 63;
    const int w    = tid >> 6;
    const int quad = lane >> 4, l15 = lane & 15;
    const int sw   = l15 & 7;
    const int wr2  = (w >> 2) * 64;   // wave row offset within a 128-row half
    const int wc2  = (w & 3) * 32;    // wave col offset within a 128-col half
    const int nt   = N >> 8;
    const int nwg  = (int)gridDim.x;  // divisible by 8 (144 / 112)
    const int bid  = (int)blockIdx.x;
    const int swz  = (bid & 7) * (nwg >> 3) + (bid >> 3);   // XCD-aware, bijective
    const int bm   = swz / nt, bn = swz % nt;
    const int NT   = K >> 6;          // 56 K-tiles

    // DMA source (slot 0 granule = tid; slot 1 = +64 rows). Row r granule g
    // stored at physical granule g^(r&7).
    const int rl = tid >> 3;
    const int g  = (tid & 7) ^ (rl & 7);
    const uint16_t* Ap = A + (size_t)(bm * 256 + rl) * K + g * 8;
    const uint16_t* Bp = B + (size_t)(bn * 256 + rl) * K + g * 8;
    const int wlds = w * 512;         // wave's 64-granule chunk within a half-tile

#define STAGE(PTR, LDS, TT, HH)                                                \
    {                                                                          \
        const uint16_t* _s = (PTR) + (size_t)(HH) * 128 * K + (TT) * 64;       \
        uint16_t* _d = &LDS[((((TT) & 1) * 2) + (HH)) * 8192] + wlds;          \
        gload16(_s, _d);                                                       \
        gload16(_s + (size_t)64 * K, _d + 4096);                               \
    }

#define RD_A(MH)                                                               \
    _Pragma("unroll") for (int i = 0; i < 4; ++i)                              \
    _Pragma("unroll") for (int ks = 0; ks < 2; ++ks)                           \
        af[i][ks] = *(const short8*)&Ab[(MH) * 8192 +                          \
            (wr2 + i * 16 + l15) * 64 + (((ks * 4 + quad) ^ sw) << 3)];

#define RD_B(NH)                                                               \
    _Pragma("unroll") for (int j = 0; j < 2; ++j)                              \
    _Pragma("unroll") for (int ks = 0; ks < 2; ++ks)                           \
        bf[NH][j][ks] = *(const short8*)&Bb[(NH) * 8192 +                      \
            (wc2 + j * 16 + l15) * 64 + (((ks * 4 + quad) ^ sw) << 3)];

#define MM(MH, NH)                                                             \
    __builtin_amdgcn_s_setprio(1);                                             \
    _Pragma("unroll") for (int ks = 0; ks < 2; ++ks)                           \
    _Pragma("unroll") for (int i = 0; i < 4; ++i)                              \
    _Pragma("unroll") for (int j = 0; j < 2; ++j)                              \
        acc[MH][NH][i][j] = __builtin_amdgcn_mfma_f32_16x16x32_bf16(           \
            af[i][ks], bf[NH][j][ks], acc[MH][NH][i][j], 0, 0, 0);             \
    __builtin_amdgcn_s_setprio(0);

    f32x4  acc[2][2][4][2] = {};
    short8 af[4][2];
    short8 bf[2][2][2];

    // prologue: 7 half-tiles (tile0: A0,B0,B1,A1; tile1: A0,B0,B1)
    STAGE(Ap, As, 0, 0); STAGE(Bp, Bs, 0, 0); STAGE(Bp, Bs, 0, 1); STAGE(Ap, As, 0, 1);
    STAGE(Ap, As, 1, 0); STAGE(Bp, Bs, 1, 0); STAGE(Bp, Bs, 1, 1);
    asm volatile("s_waitcnt vmcnt(6)" ::: "memory");   // tile 0 landed; 3 in flight
    __builtin_amdgcn_s_barrier();

    for (int t = 0; t < NT; ++t) {
        const int buf = t & 1;
        const uint16_t* Ab = &As[buf * 2 * 8192];
        const uint16_t* Bb = &Bs[buf * 2 * 8192];

        // ---- P1: quadrant (0,0) ----
        RD_A(0); RD_B(0);                              // 12 ds_read_b128
        if (t + 1 < NT) STAGE(Ap, As, t + 1, 1);       // A1(t+1) -> buf^1
        __builtin_amdgcn_s_barrier();
        asm volatile("s_waitcnt lgkmcnt(0)" ::: "memory");
        __builtin_amdgcn_sched_barrier(0);
        MM(0, 0);
        __builtin_amdgcn_s_barrier();

        // ---- P2: quadrant (0,1) ----
        RD_B(1);                                       // 4 ds_read_b128
        if (t + 2 < NT) STAGE(Ap, As, t + 2, 0);       // A0(t+2) -> buf (A0 last read P1)
        __builtin_amdgcn_s_barrier();
        asm volatile("s_waitcnt lgkmcnt(0)" ::: "memory");
        __builtin_amdgcn_sched_barrier(0);
        MM(0, 1);
        __builtin_amdgcn_s_barrier();

        // ---- P3: quadrant (1,0) ----
        RD_A(1);                                       // 8 ds_read_b128
        if (t + 2 < NT) STAGE(Bp, Bs, t + 2, 0);       // B0(t+2) -> buf (B0 last read P1)
        __builtin_amdgcn_s_barrier();
        asm volatile("s_waitcnt lgkmcnt(0)" ::: "memory");
        __builtin_amdgcn_sched_barrier(0);
        MM(1, 0);
        __builtin_amdgcn_s_barrier();

        // ---- P4: quadrant (1,1), all operands already in registers ----
        if (t + 2 < NT) STAGE(Bp, Bs, t + 2, 1);       // B1(t+2) -> buf (B1 last read P2)
        __builtin_amdgcn_s_barrier();
        __builtin_amdgcn_sched_barrier(0);
        MM(1, 1);
        if (t + 2 < NT) { asm volatile("s_waitcnt vmcnt(6)" ::: "memory"); }
        else            { asm volatile("s_waitcnt vmcnt(0)" ::: "memory"); }
        __builtin_amdgcn_s_barrier();                  // tile t+1 fully landed
    }

#undef STAGE
#undef RD_A
#undef RD_B
#undef MM

    // epilogue: C/D layout row = quad*4+r (A side), col = l15 (B side)
    const int col0 = bn * 256 + wc2 + l15;
    const size_t row0 = (size_t)bm * 256 + wr2 + quad * 4;
#pragma unroll
    for (int mh = 0; mh < 2; ++mh)
#pragma unroll
    for (int nh = 0; nh < 2; ++nh)
#pragma unroll
    for (int j = 0; j < 2; ++j) {
        const int col = col0 + nh * 128 + j * 16;
        float bv = 0.0f;
        if constexpr (!OUT_F32) bv = bias[col];
#pragma unroll
        for (int i = 0; i < 4; ++i)
#pragma unroll
        for (int r = 0; r < 4; ++r) {
            const size_t row = row0 + mh * 128 + i * 16 + r;
            const float v = acc[mh][nh][i][j][r] + bv;
            if constexpr (OUT_F32)
                ((float*)C)[row * ldc + col] = v;
            else
                ((uint16_t*)C)[row * ldc + col] = f2bf(v);
        }
    }
}

// ---------------- M-RoPE + repack to head-major (bf16 qkv, bias already added) ----------------
__global__ void rope_pack(const uint16_t* __restrict__ qkv,
                          const float* __restrict__ cosp, const float* __restrict__ sinp,
                          uint16_t* __restrict__ qr, uint16_t* __restrict__ kr)
{
    int idx = blockIdx.x * 256 + threadIdx.x;
    const int NQ = NHEADS * S_LEN * 64;
    const int NTOT = NQ + NKVH * S_LEN * 64;
    if (idx >= NTOT) return;
    bool isq = idx < NQ;
    int i = isq ? idx : idx - NQ;
    int d = i & 63;
    int s = (i >> 6) & (S_LEN - 1);
    int h = i >> 17;
    int col = (isq ? 0 : HID) + h * DHEAD + d;
    const uint16_t* rowp = qkv + (size_t)s * 4608;
    float x1 = __uint_as_float(((uint32_t)rowp[col]) << 16);
    float x2 = __uint_as_float(((uint32_t)rowp[col + 64]) << 16);
    int sec = d < 16 ? 0 : (d < 40 ? 1 : 2);
    size_t cb = (size_t)sec * (S_LEN * DHEAD) + (size_t)s * DHEAD + d;
    float c1 = cosp[cb],      s1 = sinp[cb];
    float c2 = cosp[cb + 64], s2 = sinp[cb + 64];
    float o1 = x1 * c1 - x2 * s1;
    float o2 = x2 * c2 + x1 * s2;
    uint16_t* dst = isq ? qr : kr;
    size_t ob = ((size_t)h * S_LEN + s) * DHEAD + d;
    dst[ob]      = f2bf(o1);
    dst[ob + 64] = f2bf(o2);
}

// ---------------- V transpose: qkv[S][4608] cols 4096.. -> vT [4][128][S] ----------------
__global__ void v_transpose(const uint16_t* __restrict__ qkv, uint16_t* __restrict__ vT)
{
    __shared__ __align__(16) uint16_t tile[64][68];
    const int tid = threadIdx.x;
    const int s0 = blockIdx.x * 64;
    const int n0 = blockIdx.y * 64;
    const int head = n0 >> 7, db = n0 & 127;
    const int rr = tid >> 4;
    const int c4 = (tid & 15) * 4;
#pragma unroll
    for (int p = 0; p < 4; ++p) {
        int row = p * 16 + rr;
        uint2 v = *(const uint2*)(qkv + (size_t)(s0 + row) * 4608 + 4096 + n0 + c4);
        *(uint2*)&tile[row][c4] = v;
    }
    __syncthreads();
#pragma unroll
    for (int p = 0; p < 4; ++p) {
        int drow = p * 16 + rr;
        uint32_t a0 = tile[c4 + 0][drow];
        uint32_t a1 = tile[c4 + 1][drow];
        uint32_t a2 = tile[c4 + 2][drow];
        uint32_t a3 = tile[c4 + 3][drow];
        uint2 v; v.x = a0 | (a1 << 16); v.y = a2 | (a3 << 16);
        *(uint2*)(vT + (size_t)(head * 128 + db + drow) * S_LEN + s0 + c4) = v;
    }
}

// ---------------- flash attention (GQA, causal), S^T dataflow, double-buffered KV ----------------
__global__ __launch_bounds__(256) void flash_attn(const uint16_t* __restrict__ qr,
                                                  const uint16_t* __restrict__ kr,
                                                  const uint16_t* __restrict__ vT,
                                                  uint16_t* __restrict__ out)
{
    __shared__ __align__(16) uint16_t Ks[2][64 * 128];   // [key][d], swizzled, 2 x 16 KB
    __shared__ __align__(16) uint16_t Vs[2][128 * 64];   // [d][key], swizzled, 2 x 16 KB
    __shared__ __align__(16) uint16_t Ps[4][16 * 72];    // per-wave P^T [qrow][key]
    const int tid = threadIdx.x;
    const int lane = tid & 63, w = tid >> 6;
    const int quad = lane >> 4, l15 = lane & 15;
    const int sw = l15 & 7;
    const int b = (int)blockIdx.x;
    const int qtp = b / 28;                  // heavy-first
    const int h = b - qtp * 28;
    const int qt = 31 - qtp;
    const int q0 = qt * 64;
    const int kvh = h / 7;                   // N_REP = 7
    const float SCL2 = 0.08838834764831845f * 1.44269504088896f;

    short8 qf[4];
    {
        const uint16_t* qb = qr + ((size_t)h * S_LEN + q0 + w * 16 + l15) * DHEAD;
#pragma unroll
        for (int ks = 0; ks < 4; ++ks)
            qf[ks] = *(const short8*)(qb + ks * 32 + quad * 8);
    }

    const uint16_t* Kgp[4];
    const uint16_t* Vgp[4];
    {
        const uint16_t* kbase = kr + (size_t)kvh * S_LEN * DHEAD;
        const uint16_t* vbase = vT + (size_t)kvh * DHEAD * S_LEN;
#pragma unroll
        for (int i = 0; i < 4; ++i) {
            int sg = w * 256 + i * 64 + lane;
            int rowk = sg >> 4;
            int gk = (sg & 8) | ((sg ^ rowk) & 7);
            Kgp[i] = kbase + (size_t)rowk * DHEAD + gk * 8;
            int rowv = sg >> 3;
            int gv = (sg ^ rowv) & 7;
            Vgp[i] = vbase + (size_t)rowv * S_LEN + gv * 8;
        }
    }
    const int ksoff = w * 2048;

    f32x4 o[8] = {};
    float m_i = -1.0e30f, l_i = 0.0f;

    // prologue: stage KV tile 0 into buffer 0
#pragma unroll
    for (int i = 0; i < 4; ++i) gload16(Kgp[i], &Ks[0][ksoff] + i * 512);
#pragma unroll
    for (int i = 0; i < 4; ++i) gload16(Vgp[i], &Vs[0][ksoff] + i * 512);

    int buf = 0;
    for (int kt = 0; kt <= qt; ++kt) {
        __syncthreads();                      // drains DMA(buf); prev reads of buf^1 done
        if (kt < qt) {                        // prefetch next KV tile into buf^1
            const int offk = (kt + 1) * 64 * DHEAD;
            const int offv = (kt + 1) * 64;
#pragma unroll
            for (int i = 0; i < 4; ++i) gload16(Kgp[i] + offk, &Ks[buf ^ 1][ksoff] + i * 512);
#pragma unroll
            for (int i = 0; i < 4; ++i) gload16(Vgp[i] + offv, &Vs[buf ^ 1][ksoff] + i * 512);
        }
        const uint16_t* Kc = &Ks[buf][0];
        const uint16_t* Vc = &Vs[buf][0];

        // S^T = K Q^T : D[key on quad*4+r][qrow on l15]
        f32x4 sc[4] = {};
#pragma unroll
        for (int j = 0; j < 4; ++j)
#pragma unroll
            for (int ks = 0; ks < 4; ++ks) {
                int g = ks * 4 + quad;
                int gp = (g & 8) | ((g ^ sw) & 7);
                short8 kf = *(const short8*)&Kc[(j * 16 + l15) * 128 + gp * 8];
                sc[j] = __builtin_amdgcn_mfma_f32_16x16x32_bf16(kf, qf[ks], sc[j], 0, 0, 0);
            }

        // scale (base-2) + causal mask (diag tile only)
        if (kt == qt) {
            int qrel = w * 16 + l15;
#pragma unroll
            for (int j = 0; j < 4; ++j)
#pragma unroll
                for (int r = 0; r < 4; ++r) {
                    int krel = j * 16 + quad * 4 + r;
                    sc[j][r] = (krel <= qrel) ? sc[j][r] * SCL2 : -1.0e30f;
                }
        } else {
#pragma unroll
            for (int j = 0; j < 4; ++j)
#pragma unroll
                for (int r = 0; r < 4; ++r) sc[j][r] *= SCL2;
        }

        // row max: in-register tree, then cross-quad (xor16, xor32)
        float mx;
        {
            float m0 = fmaxf(fmaxf(sc[0][0], sc[0][1]), fmaxf(sc[0][2], sc[0][3]));
            float m1 = fmaxf(fmaxf(sc[1][0], sc[1][1]), fmaxf(sc[1][2], sc[1][3]));
            float m2 = fmaxf(fmaxf(sc[2][0], sc[2][1]), fmaxf(sc[2][2], sc[2][3]));
            float m3 = fmaxf(fmaxf(sc[3][0], sc[3][1]), fmaxf(sc[3][2], sc[3][3]));
            mx = fmaxf(fmaxf(m0, m1), fmaxf(m2, m3));
        }
        mx = fmaxf(mx, __shfl_xor(mx, 16));
        mx = fmaxf(mx, __shfl_xor(mx, 32));
        float mn = fmaxf(m_i, mx);
        float alpha = exp2f(m_i - mn);
        m_i = mn;
        float s = 0.0f;
#pragma unroll
        for (int j = 0; j < 4; ++j)
#pragma unroll
            for (int r = 0; r < 4; ++r) {
                float p = exp2f(sc[j][r] - mn);
                sc[j][r] = p;
                s += p;
            }
        s += __shfl_xor(s, 16);
        s += __shfl_xor(s, 32);
        l_i = l_i * alpha + s;
#pragma unroll
        for (int jd = 0; jd < 8; ++jd)
#pragma unroll
            for (int r = 0; r < 4; ++r) o[jd][r] *= alpha;

        // pack P^T[qrow][key] (per-wave buf, same-wave LDS ordering)
#pragma unroll
        for (int j = 0; j < 4; ++j) {
            uint2 p2;
            p2.x = (uint32_t)f2bf(sc[j][0]) | ((uint32_t)f2bf(sc[j][1]) << 16);
            p2.y = (uint32_t)f2bf(sc[j][2]) | ((uint32_t)f2bf(sc[j][3]) << 16);
            *(uint2*)&Ps[w][l15 * 72 + j * 16 + quad * 4] = p2;
        }

        // O^T += V^T P^T
#pragma unroll
        for (int k2 = 0; k2 < 2; ++k2) {
            short8 pf = *(const short8*)&Ps[w][l15 * 72 + k2 * 32 + quad * 8];
#pragma unroll
            for (int jd = 0; jd < 8; ++jd) {
                int g = k2 * 4 + quad;
                int gp = (g ^ sw) & 7;
                short8 vf = *(const short8*)&Vc[(jd * 16 + l15) * 64 + gp * 8];
                o[jd] = __builtin_amdgcn_mfma_f32_16x16x32_bf16(vf, pf, o[jd], 0, 0, 0);
            }
        }
        buf ^= 1;
    }

    float inv = 1.0f / l_i;
    uint16_t* ob = out + (size_t)(q0 + w * 16 + l15) * HID + h * DHEAD + quad * 4;
#pragma unroll
    for (int jd = 0; jd < 8; ++jd) {
        uint2 p2;
        p2.x = (uint32_t)f2bf(o[jd][0] * inv) | ((uint32_t)f2bf(o[jd][1] * inv) << 16);
        p2.y = (uint32_t)f2bf(o[jd][2] * inv) | ((uint32_t)f2bf(o[jd][3] * inv) << 16);
        *(uint2*)(ob + jd * 16) = p2;
    }
}

// ---------------- launch ----------------
extern "C" void kernel_launch(void* const* d_in, const int* in_sizes, int n_in,
                              void* d_out, int out_size, void* d_ws, size_t ws_size,
                              hipStream_t stream)
{
    const float* hs   = (const float*)d_in[0];
    const float* Wq   = (const float*)d_in[1];
    const float* bq   = (const float*)d_in[2];
    const float* Wk   = (const float*)d_in[3];
    const float* bk   = (const float*)d_in[4];
    const float* Wv   = (const float*)d_in[5];
    const float* bv   = (const float*)d_in[6];
    const float* Wo   = (const float*)d_in[7];
    const float* cosp = (const float*)d_in[8];
    const float* sinp = (const float*)d_in[9];

    char* ws = (char*)d_ws;
    uint16_t* hs_bf   = (uint16_t*)(ws + 0);           // 2048*3584 bf16
    uint16_t* wqkv_bf = (uint16_t*)(ws + 14680064);    // 4608*3584 bf16
    uint16_t* wo_bf   = (uint16_t*)(ws + 47710208);    // 3584*3584 bf16
    uint16_t* qkv_buf = (uint16_t*)(ws + 73400320);    // 2048*4608 bf16; later attn_out
    uint16_t* qr      = (uint16_t*)(ws + 92274688);    // 28*2048*128 bf16
    uint16_t* kr      = (uint16_t*)(ws + 106954752);   // 4*2048*128 bf16
    uint16_t* vT      = (uint16_t*)(ws + 109051904);   // 4*128*2048 bf16
    float*    biasq   = (float*)(ws + 111149056);      // 4608 f32

    cvt_all<<<35840, 256, 0, stream>>>(hs, Wq, Wk, Wv, Wo, hs_bf, wqkv_bf, wo_bf);
    concat_bias<<<18, 256, 0, stream>>>(bq, bk, bv, biasq);

    // QKV projection: 8x18 = 144 blocks (256^2 tile), 8-phase counted-vmcnt
    gemm_bt256<false><<<144, 512, 0, stream>>>(hs_bf, wqkv_bf, biasq, qkv_buf, 4608, 3584, 4608);

    rope_pack<<<16384, 256, 0, stream>>>(qkv_buf, cosp, sinp, qr, kr);
    v_transpose<<<dim3(32, 8), 256, 0, stream>>>(qkv_buf, vT);

    flash_attn<<<896, 256, 0, stream>>>(qr, kr, vT, qkv_buf);

    // output projection: 8x14 = 112 blocks (256^2 tile)
    gemm_bt256<true><<<112, 512, 0, stream>>>(qkv_buf, wo_bf, nullptr, d_out, 3584, 3584, 3584);
}

// Round 7
// 446.108 us; speedup vs baseline: 1.0486x; 1.0486x over previous
//
#include <hip/hip_runtime.h>
#include <stdint.h>

#define S_LEN 2048
#define HID 3584
#define NHEADS 28
#define NKVH 4
#define DHEAD 128

typedef __attribute__((ext_vector_type(8))) short short8;
typedef __attribute__((ext_vector_type(4))) float f32x4;

__device__ __forceinline__ uint16_t f2bf(float f) {
    uint32_t u = __float_as_uint(f);
    u += 0x7fffu + ((u >> 16) & 1u);   // RNE
    return (uint16_t)(u >> 16);
}

// async global->LDS DMA, 16B per lane; LDS dest = wave-uniform base + lane*16
__device__ __forceinline__ void gload16(const uint16_t* g, uint16_t* l) {
    __builtin_amdgcn_global_load_lds(
        (const __attribute__((address_space(1))) uint32_t*)g,
        (__attribute__((address_space(3))) uint32_t*)l, 16, 0, 0);
}

// ---------------- fused fp32 -> bf16 conversion (all 5 tensors, 1 launch) ----------------
#define C_HS 1835008
#define C_WQ 5046272
#define C_WK 5505024
#define C_WV 5963776
#define C_TOT 9175040
__global__ void cvt_all(const float* __restrict__ hs, const float* __restrict__ Wq,
                        const float* __restrict__ Wk, const float* __restrict__ Wv,
                        const float* __restrict__ Wo,
                        uint16_t* __restrict__ hs_bf, uint16_t* __restrict__ wqkv_bf,
                        uint16_t* __restrict__ wo_bf) {
    int i = blockIdx.x * 256 + threadIdx.x;
    if (i >= C_TOT) return;
    const float* src; uint16_t* dst; int off;
    if (i < C_HS)      { src = hs; dst = hs_bf;               off = i; }
    else if (i < C_WQ) { src = Wq; dst = wqkv_bf;             off = i - C_HS; }
    else if (i < C_WK) { src = Wk; dst = wqkv_bf + 12845056;  off = i - C_WQ; }
    else if (i < C_WV) { src = Wv; dst = wqkv_bf + 14680064;  off = i - C_WK; }
    else               { src = Wo; dst = wo_bf;               off = i - C_WV; }
    float4 f = ((const float4*)src)[off];
    uint2 v;
    v.x = (uint32_t)f2bf(f.x) | ((uint32_t)f2bf(f.y) << 16);
    v.y = (uint32_t)f2bf(f.z) | ((uint32_t)f2bf(f.w) << 16);
    *(uint2*)(dst + (size_t)off * 4) = v;
}

__global__ void concat_bias(const float* __restrict__ bq, const float* __restrict__ bk,
                            const float* __restrict__ bv, float* __restrict__ dst) {
    int i = blockIdx.x * 256 + threadIdx.x;
    if (i < 3584) dst[i] = bq[i];
    else if (i < 4096) dst[i] = bk[i - 3584];
    else if (i < 4608) dst[i] = bv[i - 4096];
}

// ---------------- bf16 GEMM: C = A * B^T (+bias) ----------------
// 256x256 tile, BK=64, 8 waves / 512 threads, 128 KiB LDS; 8-phase schedule with
// counted vmcnt(6) (never 0 in steady state) + s_setprio (T3+T4+T5).
// SPLITK=2 (out-proj): grid = 2 x 112; kslice 0 -> XCDs 0-3, kslice 1 -> XCDs 4-7.
// f32 partials land in DEAD workspace regions (see kernel_launch comments):
//   kslice0: ws+0                              (rows 0..2047)
//   kslice1: ws+29360128 (rows 0..1279)  /  ws+92274688 (rows 1280..2047)
// A block's rows are uniform in chunk (bm<5 vs >=5) since 1280 = 5*256.
template <bool OUT_F32, int SPLITK>
__global__ __launch_bounds__(512, 2) void gemm_bt256(const uint16_t* __restrict__ A,
                                                     const uint16_t* __restrict__ B,
                                                     const float* __restrict__ bias,
                                                     void* __restrict__ C,
                                                     int N, int K, int ldc)
{
    __shared__ __align__(16) uint16_t As[4 * 8192];   // [buf][half][128*64] = 64 KB
    __shared__ __align__(16) uint16_t Bs[4 * 8192];   // 64 KB
    const int tid  = threadIdx.x;
    const int lane = tid & 63;
    const int w    = tid >> 6;
    const int quad = lane >> 4, l15 = lane & 15;
    const int sw   = l15 & 7;
    const int wr2  = (w >> 2) * 64;   // wave row offset within a 128-row half
    const int wc2  = (w & 3) * 32;    // wave col offset within a 128-col half
    const int nt   = N >> 8;
    const int nwg  = (int)gridDim.x;  // divisible by 8 (144 / 224)
    const int bid  = (int)blockIdx.x;
    const int swz  = (bid & 7) * (nwg >> 3) + (bid >> 3);   // XCD-aware, bijective
    int rem = swz, kslice = 0;
    if constexpr (SPLITK == 2) { kslice = swz / (nwg >> 1); rem = swz - kslice * (nwg >> 1); }
    const int bm   = rem / nt, bn = rem % nt;
    const int Keff = K / SPLITK;
    const int NT   = Keff >> 6;       // K-tiles for this slice
    const int k0   = kslice * Keff;

    // DMA source (slot 0 granule = tid; slot 1 = +64 rows). Row r granule g
    // stored at physical granule g^(r&7).
    const int rl = tid >> 3;
    const int g  = (tid & 7) ^ (rl & 7);
    const uint16_t* Ap = A + (size_t)(bm * 256 + rl) * K + k0 + g * 8;
    const uint16_t* Bp = B + (size_t)(bn * 256 + rl) * K + k0 + g * 8;
    const int wlds = w * 512;         // wave's 64-granule chunk within a half-tile

#define STAGE(PTR, LDS, TT, HH)                                                \
    {                                                                          \
        const uint16_t* _s = (PTR) + (size_t)(HH) * 128 * K + (TT) * 64;       \
        uint16_t* _d = &LDS[((((TT) & 1) * 2) + (HH)) * 8192] + wlds;          \
        gload16(_s, _d);                                                       \
        gload16(_s + (size_t)64 * K, _d + 4096);                               \
    }

#define RD_A(MH)                                                               \
    _Pragma("unroll") for (int i = 0; i < 4; ++i)                              \
    _Pragma("unroll") for (int ks = 0; ks < 2; ++ks)                           \
        af[i][ks] = *(const short8*)&Ab[(MH) * 8192 +                          \
            (wr2 + i * 16 + l15) * 64 + (((ks * 4 + quad) ^ sw) << 3)];

#define RD_B(NH)                                                               \
    _Pragma("unroll") for (int j = 0; j < 2; ++j)                              \
    _Pragma("unroll") for (int ks = 0; ks < 2; ++ks)                           \
        bf[NH][j][ks] = *(const short8*)&Bb[(NH) * 8192 +                      \
            (wc2 + j * 16 + l15) * 64 + (((ks * 4 + quad) ^ sw) << 3)];

#define MM(MH, NH)                                                             \
    __builtin_amdgcn_s_setprio(1);                                             \
    _Pragma("unroll") for (int ks = 0; ks < 2; ++ks)                           \
    _Pragma("unroll") for (int i = 0; i < 4; ++i)                              \
    _Pragma("unroll") for (int j = 0; j < 2; ++j)                              \
        acc[MH][NH][i][j] = __builtin_amdgcn_mfma_f32_16x16x32_bf16(           \
            af[i][ks], bf[NH][j][ks], acc[MH][NH][i][j], 0, 0, 0);             \
    __builtin_amdgcn_s_setprio(0);

    f32x4  acc[2][2][4][2] = {};
    short8 af[4][2];
    short8 bf[2][2][2];

    // prologue: 7 half-tiles (tile0: A0,B0,B1,A1; tile1: A0,B0,B1)
    STAGE(Ap, As, 0, 0); STAGE(Bp, Bs, 0, 0); STAGE(Bp, Bs, 0, 1); STAGE(Ap, As, 0, 1);
    STAGE(Ap, As, 1, 0); STAGE(Bp, Bs, 1, 0); STAGE(Bp, Bs, 1, 1);
    asm volatile("s_waitcnt vmcnt(6)" ::: "memory");   // tile 0 landed; 3 in flight
    __builtin_amdgcn_s_barrier();

    for (int t = 0; t < NT; ++t) {
        const int buf = t & 1;
        const uint16_t* Ab = &As[buf * 2 * 8192];
        const uint16_t* Bb = &Bs[buf * 2 * 8192];

        // ---- P1: quadrant (0,0) ----
        RD_A(0); RD_B(0);                              // 12 ds_read_b128
        if (t + 1 < NT) STAGE(Ap, As, t + 1, 1);       // A1(t+1) -> buf^1
        asm volatile("s_waitcnt lgkmcnt(8)" ::: "memory");  // pace the 12-read phase (m201)
        __builtin_amdgcn_s_barrier();
        asm volatile("s_waitcnt lgkmcnt(0)" ::: "memory");
        __builtin_amdgcn_sched_barrier(0);
        MM(0, 0);
        __builtin_amdgcn_s_barrier();

        // ---- P2: quadrant (0,1) ----
        RD_B(1);                                       // 4 ds_read_b128
        if (t + 2 < NT) STAGE(Ap, As, t + 2, 0);       // A0(t+2) -> buf (A0 last read P1)
        __builtin_amdgcn_s_barrier();
        asm volatile("s_waitcnt lgkmcnt(0)" ::: "memory");
        __builtin_amdgcn_sched_barrier(0);
        MM(0, 1);
        __builtin_amdgcn_s_barrier();

        // ---- P3: quadrant (1,0) ----
        RD_A(1);                                       // 8 ds_read_b128
        if (t + 2 < NT) STAGE(Bp, Bs, t + 2, 0);       // B0(t+2) -> buf (B0 last read P1)
        __builtin_amdgcn_s_barrier();
        asm volatile("s_waitcnt lgkmcnt(0)" ::: "memory");
        __builtin_amdgcn_sched_barrier(0);
        MM(1, 0);
        __builtin_amdgcn_s_barrier();

        // ---- P4: quadrant (1,1), all operands already in registers ----
        if (t + 2 < NT) STAGE(Bp, Bs, t + 2, 1);       // B1(t+2) -> buf (B1 last read P2)
        __builtin_amdgcn_s_barrier();
        __builtin_amdgcn_sched_barrier(0);
        MM(1, 1);
        if (t + 2 < NT) { asm volatile("s_waitcnt vmcnt(6)" ::: "memory"); }
        else            { asm volatile("s_waitcnt vmcnt(0)" ::: "memory"); }
        __builtin_amdgcn_s_barrier();                  // tile t+1 fully landed
    }

#undef STAGE
#undef RD_A
#undef RD_B
#undef MM

    // epilogue: C/D layout row = quad*4+r (A side), col = l15 (B side)
    const int col0 = bn * 256 + wc2 + l15;
    const size_t row0 = (size_t)bm * 256 + wr2 + quad * 4;

    if constexpr (SPLITK == 2) {
        // f32 partials into dead workspace regions; no bias in split mode.
        char* Cc = (char*)C;
        float* pb;
        if (kslice == 0) pb = (float*)Cc;
        else if (bm < 5) pb = (float*)(Cc + 29360128);
        else             pb = (float*)(Cc + 92274688) - (size_t)1280 * 3584;
#pragma unroll
        for (int mh = 0; mh < 2; ++mh)
#pragma unroll
        for (int nh = 0; nh < 2; ++nh)
#pragma unroll
        for (int j = 0; j < 2; ++j) {
            const int col = col0 + nh * 128 + j * 16;
#pragma unroll
            for (int i = 0; i < 4; ++i)
#pragma unroll
            for (int r = 0; r < 4; ++r) {
                const size_t row = row0 + mh * 128 + i * 16 + r;
                pb[row * ldc + col] = acc[mh][nh][i][j][r];
            }
        }
    } else {
#pragma unroll
        for (int mh = 0; mh < 2; ++mh)
#pragma unroll
        for (int nh = 0; nh < 2; ++nh)
#pragma unroll
        for (int j = 0; j < 2; ++j) {
            const int col = col0 + nh * 128 + j * 16;
            float bv = 0.0f;
            if constexpr (!OUT_F32) bv = bias[col];
#pragma unroll
            for (int i = 0; i < 4; ++i)
#pragma unroll
            for (int r = 0; r < 4; ++r) {
                const size_t row = row0 + mh * 128 + i * 16 + r;
                const float v = acc[mh][nh][i][j][r] + bv;
                if constexpr (OUT_F32)
                    ((float*)C)[row * ldc + col] = v;
                else
                    ((uint16_t*)C)[row * ldc + col] = f2bf(v);
            }
        }
    }
}

// ---------------- split-K reduction: d_out = P0 + P1 (f32) ----------------
// P0 = ws+0; P1 = ws+29360128 (float idx < 1280*3584) else ws+92274688 chunk.
__global__ void reduce_out(const char* __restrict__ ws, float* __restrict__ out)
{
    int i = blockIdx.x * 256 + threadIdx.x;          // float4 index, 1,835,008 total
    const f32x4 a = ((const f32x4*)ws)[i];
    const size_t fi = (size_t)i * 4;
    const float* hi = (fi < (size_t)1280 * 3584)
                        ? (const float*)(ws + 29360128)
                        : (const float*)(ws + 92274688) - (size_t)1280 * 3584;
    const f32x4 b = *(const f32x4*)(hi + fi);
    ((f32x4*)out)[i] = a + b;
}

// ---------------- M-RoPE + repack to head-major, vectorized x4 ----------------
__global__ void rope_pack4(const uint16_t* __restrict__ qkv,
                           const float* __restrict__ cosp, const float* __restrict__ sinp,
                           uint16_t* __restrict__ qr, uint16_t* __restrict__ kr)
{
    int idx = blockIdx.x * 256 + threadIdx.x;        // quad index
    const int NQ4 = NHEADS * S_LEN * 16;             // 917504
    bool isq = idx < NQ4;
    int i = isq ? idx : idx - NQ4;
    int d4 = (i & 15) * 4;                           // d base (sec uniform: 16,40 are mult of 4)
    int s  = (i >> 4) & (S_LEN - 1);
    int h  = i >> 15;
    int col = (isq ? 0 : HID) + h * DHEAD + d4;
    const uint16_t* rowp = qkv + (size_t)s * 4608;
    uint2 x1v = *(const uint2*)(rowp + col);
    uint2 x2v = *(const uint2*)(rowp + col + 64);
    int sec = d4 < 16 ? 0 : (d4 < 40 ? 1 : 2);
    size_t cb = (size_t)sec * (S_LEN * DHEAD) + (size_t)s * DHEAD + d4;
    float4 c1 = *(const float4*)(cosp + cb),      s1 = *(const float4*)(sinp + cb);
    float4 c2 = *(const float4*)(cosp + cb + 64), s2 = *(const float4*)(sinp + cb + 64);
    float x1[4], x2[4];
    x1[0] = __uint_as_float((x1v.x & 0xffffu) << 16); x1[1] = __uint_as_float(x1v.x & 0xffff0000u);
    x1[2] = __uint_as_float((x1v.y & 0xffffu) << 16); x1[3] = __uint_as_float(x1v.y & 0xffff0000u);
    x2[0] = __uint_as_float((x2v.x & 0xffffu) << 16); x2[1] = __uint_as_float(x2v.x & 0xffff0000u);
    x2[2] = __uint_as_float((x2v.y & 0xffffu) << 16); x2[3] = __uint_as_float(x2v.y & 0xffff0000u);
    float o1[4], o2[4];
    o1[0] = x1[0]*c1.x - x2[0]*s1.x;  o2[0] = x2[0]*c2.x + x1[0]*s2.x;
    o1[1] = x1[1]*c1.y - x2[1]*s1.y;  o2[1] = x2[1]*c2.y + x1[1]*s2.y;
    o1[2] = x1[2]*c1.z - x2[2]*s1.z;  o2[2] = x2[2]*c2.z + x1[2]*s2.z;
    o1[3] = x1[3]*c1.w - x2[3]*s1.w;  o2[3] = x2[3]*c2.w + x1[3]*s2.w;
    uint16_t* dst = isq ? qr : kr;
    size_t ob = ((size_t)h * S_LEN + s) * DHEAD + d4;
    uint2 w1, w2;
    w1.x = (uint32_t)f2bf(o1[0]) | ((uint32_t)f2bf(o1[1]) << 16);
    w1.y = (uint32_t)f2bf(o1[2]) | ((uint32_t)f2bf(o1[3]) << 16);
    w2.x = (uint32_t)f2bf(o2[0]) | ((uint32_t)f2bf(o2[1]) << 16);
    w2.y = (uint32_t)f2bf(o2[2]) | ((uint32_t)f2bf(o2[3]) << 16);
    *(uint2*)(dst + ob)      = w1;
    *(uint2*)(dst + ob + 64) = w2;
}

// ---------------- V transpose: qkv[S][4608] cols 4096.. -> vT [4][128][S] ----------------
__global__ void v_transpose(const uint16_t* __restrict__ qkv, uint16_t* __restrict__ vT)
{
    __shared__ __align__(16) uint16_t tile[64][68];
    const int tid = threadIdx.x;
    const int s0 = blockIdx.x * 64;
    const int n0 = blockIdx.y * 64;
    const int head = n0 >> 7, db = n0 & 127;
    const int rr = tid >> 4;
    const int c4 = (tid & 15) * 4;
#pragma unroll
    for (int p = 0; p < 4; ++p) {
        int row = p * 16 + rr;
        uint2 v = *(const uint2*)(qkv + (size_t)(s0 + row) * 4608 + 4096 + n0 + c4);
        *(uint2*)&tile[row][c4] = v;
    }
    __syncthreads();
#pragma unroll
    for (int p = 0; p < 4; ++p) {
        int drow = p * 16 + rr;
        uint32_t a0 = tile[c4 + 0][drow];
        uint32_t a1 = tile[c4 + 1][drow];
        uint32_t a2 = tile[c4 + 2][drow];
        uint32_t a3 = tile[c4 + 3][drow];
        uint2 v; v.x = a0 | (a1 << 16); v.y = a2 | (a3 << 16);
        *(uint2*)(vT + (size_t)(head * 128 + db + drow) * S_LEN + s0 + c4) = v;
    }
}

// ---------------- flash attention (GQA, causal), S^T dataflow, double-buffered KV ----------------
__global__ __launch_bounds__(256) void flash_attn(const uint16_t* __restrict__ qr,
                                                  const uint16_t* __restrict__ kr,
                                                  const uint16_t* __restrict__ vT,
                                                  uint16_t* __restrict__ out)
{
    __shared__ __align__(16) uint16_t Ks[2][64 * 128];   // [key][d], swizzled, 2 x 16 KB
    __shared__ __align__(16) uint16_t Vs[2][128 * 64];   // [d][key], swizzled, 2 x 16 KB
    __shared__ __align__(16) uint16_t Ps[4][16 * 72];    // per-wave P^T [qrow][key]
    const int tid = threadIdx.x;
    const int lane = tid & 63, w = tid >> 6;
    const int quad = lane >> 4, l15 = lane & 15;
    const int sw = l15 & 7;
    const int b = (int)blockIdx.x;
    const int qtp = b / 28;                  // heavy-first
    const int h = b - qtp * 28;
    const int qt = 31 - qtp;
    const int q0 = qt * 64;
    const int kvh = h / 7;                   // N_REP = 7
    const float SCL2 = 0.08838834764831845f * 1.44269504088896f;

    short8 qf[4];
    {
        const uint16_t* qb = qr + ((size_t)h * S_LEN + q0 + w * 16 + l15) * DHEAD;
#pragma unroll
        for (int ks = 0; ks < 4; ++ks)
            qf[ks] = *(const short8*)(qb + ks * 32 + quad * 8);
    }

    const uint16_t* Kgp[4];
    const uint16_t* Vgp[4];
    {
        const uint16_t* kbase = kr + (size_t)kvh * S_LEN * DHEAD;
        const uint16_t* vbase = vT + (size_t)kvh * DHEAD * S_LEN;
#pragma unroll
        for (int i = 0; i < 4; ++i) {
            int sg = w * 256 + i * 64 + lane;
            int rowk = sg >> 4;
            int gk = (sg & 8) | ((sg ^ rowk) & 7);
            Kgp[i] = kbase + (size_t)rowk * DHEAD + gk * 8;
            int rowv = sg >> 3;
            int gv = (sg ^ rowv) & 7;
            Vgp[i] = vbase + (size_t)rowv * S_LEN + gv * 8;
        }
    }
    const int ksoff = w * 2048;

    f32x4 o[8] = {};
    float m_i = -1.0e30f, l_i = 0.0f;

    // prologue: stage KV tile 0 into buffer 0
#pragma unroll
    for (int i = 0; i < 4; ++i) gload16(Kgp[i], &Ks[0][ksoff] + i * 512);
#pragma unroll
    for (int i = 0; i < 4; ++i) gload16(Vgp[i], &Vs[0][ksoff] + i * 512);

    int buf = 0;
    for (int kt = 0; kt <= qt; ++kt) {
        __syncthreads();                      // drains DMA(buf); prev reads of buf^1 done
        if (kt < qt) {                        // prefetch next KV tile into buf^1
            const int offk = (kt + 1) * 64 * DHEAD;
            const int offv = (kt + 1) * 64;
#pragma unroll
            for (int i = 0; i < 4; ++i) gload16(Kgp[i] + offk, &Ks[buf ^ 1][ksoff] + i * 512);
#pragma unroll
            for (int i = 0; i < 4; ++i) gload16(Vgp[i] + offv, &Vs[buf ^ 1][ksoff] + i * 512);
        }
        const uint16_t* Kc = &Ks[buf][0];
        const uint16_t* Vc = &Vs[buf][0];

        // S^T = K Q^T : D[key on quad*4+r][qrow on l15]
        f32x4 sc[4] = {};
#pragma unroll
        for (int j = 0; j < 4; ++j)
#pragma unroll
            for (int ks = 0; ks < 4; ++ks) {
                int g = ks * 4 + quad;
                int gp = (g & 8) | ((g ^ sw) & 7);
                short8 kf = *(const short8*)&Kc[(j * 16 + l15) * 128 + gp * 8];
                sc[j] = __builtin_amdgcn_mfma_f32_16x16x32_bf16(kf, qf[ks], sc[j], 0, 0, 0);
            }

        // scale (base-2) + causal mask (diag tile only)
        if (kt == qt) {
            int qrel = w * 16 + l15;
#pragma unroll
            for (int j = 0; j < 4; ++j)
#pragma unroll
                for (int r = 0; r < 4; ++r) {
                    int krel = j * 16 + quad * 4 + r;
                    sc[j][r] = (krel <= qrel) ? sc[j][r] * SCL2 : -1.0e30f;
                }
        } else {
#pragma unroll
            for (int j = 0; j < 4; ++j)
#pragma unroll
                for (int r = 0; r < 4; ++r) sc[j][r] *= SCL2;
        }

        // row max: in-register tree, then cross-quad (xor16, xor32)
        float mx;
        {
            float m0 = fmaxf(fmaxf(sc[0][0], sc[0][1]), fmaxf(sc[0][2], sc[0][3]));
            float m1 = fmaxf(fmaxf(sc[1][0], sc[1][1]), fmaxf(sc[1][2], sc[1][3]));
            float m2 = fmaxf(fmaxf(sc[2][0], sc[2][1]), fmaxf(sc[2][2], sc[2][3]));
            float m3 = fmaxf(fmaxf(sc[3][0], sc[3][1]), fmaxf(sc[3][2], sc[3][3]));
            mx = fmaxf(fmaxf(m0, m1), fmaxf(m2, m3));
        }
        mx = fmaxf(mx, __shfl_xor(mx, 16));
        mx = fmaxf(mx, __shfl_xor(mx, 32));

        // T13 defer-max: skip O/l rescale when no row's max grew by >7 (base-2):
        // P then bounded by 2^7=128 -- safe in bf16/f32. Wave-uniform branch.
        float mn = fmaxf(m_i, mx);
        if (!__all(mn - m_i <= 7.0f)) {
            float alpha = exp2f(m_i - mn);
            m_i = mn;
            l_i *= alpha;
#pragma unroll
            for (int jd = 0; jd < 8; ++jd)
#pragma unroll
                for (int r = 0; r < 4; ++r) o[jd][r] *= alpha;
        }
        float s = 0.0f;
#pragma unroll
        for (int j = 0; j < 4; ++j)
#pragma unroll
            for (int r = 0; r < 4; ++r) {
                float p = exp2f(sc[j][r] - m_i);
                sc[j][r] = p;
                s += p;
            }
        s += __shfl_xor(s, 16);
        s += __shfl_xor(s, 32);
        l_i += s;

        // pack P^T[qrow][key] (per-wave buf, same-wave LDS ordering)
#pragma unroll
        for (int j = 0; j < 4; ++j) {
            uint2 p2;
            p2.x = (uint32_t)f2bf(sc[j][0]) | ((uint32_t)f2bf(sc[j][1]) << 16);
            p2.y = (uint32_t)f2bf(sc[j][2]) | ((uint32_t)f2bf(sc[j][3]) << 16);
            *(uint2*)&Ps[w][l15 * 72 + j * 16 + quad * 4] = p2;
        }

        // O^T += V^T P^T
#pragma unroll
        for (int k2 = 0; k2 < 2; ++k2) {
            short8 pf = *(const short8*)&Ps[w][l15 * 72 + k2 * 32 + quad * 8];
#pragma unroll
            for (int jd = 0; jd < 8; ++jd) {
                int g = k2 * 4 + quad;
                int gp = (g ^ sw) & 7;
                short8 vf = *(const short8*)&Vc[(jd * 16 + l15) * 64 + gp * 8];
                o[jd] = __builtin_amdgcn_mfma_f32_16x16x32_bf16(vf, pf, o[jd], 0, 0, 0);
            }
        }
        buf ^= 1;
    }

    float inv = 1.0f / l_i;
    uint16_t* ob = out + (size_t)(q0 + w * 16 + l15) * HID + h * DHEAD + quad * 4;
#pragma unroll
    for (int jd = 0; jd < 8; ++jd) {
        uint2 p2;
        p2.x = (uint32_t)f2bf(o[jd][0] * inv) | ((uint32_t)f2bf(o[jd][1] * inv) << 16);
        p2.y = (uint32_t)f2bf(o[jd][2] * inv) | ((uint32_t)f2bf(o[jd][3] * inv) << 16);
        *(uint2*)(ob + jd * 16) = p2;
    }
}

// ---------------- launch ----------------
extern "C" void kernel_launch(void* const* d_in, const int* in_sizes, int n_in,
                              void* d_out, int out_size, void* d_ws, size_t ws_size,
                              hipStream_t stream)
{
    const float* hs   = (const float*)d_in[0];
    const float* Wq   = (const float*)d_in[1];
    const float* bq   = (const float*)d_in[2];
    const float* Wk   = (const float*)d_in[3];
    const float* bk   = (const float*)d_in[4];
    const float* Wv   = (const float*)d_in[5];
    const float* bv   = (const float*)d_in[6];
    const float* Wo   = (const float*)d_in[7];
    const float* cosp = (const float*)d_in[8];
    const float* sinp = (const float*)d_in[9];

    char* ws = (char*)d_ws;
    uint16_t* hs_bf   = (uint16_t*)(ws + 0);           // 2048*3584 bf16 (dead after QKV gemm)
    uint16_t* wqkv_bf = (uint16_t*)(ws + 14680064);    // 4608*3584 bf16 (dead after QKV gemm)
    uint16_t* wo_bf   = (uint16_t*)(ws + 47710208);    // 3584*3584 bf16 (live until out-proj)
    uint16_t* qkv_buf = (uint16_t*)(ws + 73400320);    // 2048*4608 bf16; later attn_out (live)
    uint16_t* qr      = (uint16_t*)(ws + 92274688);    // 28*2048*128 bf16 (dead after attn)
    uint16_t* kr      = (uint16_t*)(ws + 106954752);   // 4*2048*128 bf16 (dead after attn)
    uint16_t* vT      = (uint16_t*)(ws + 109051904);   // 4*128*2048 bf16 (dead after attn)
    float*    biasq   = (float*)(ws + 111149056);      // 4608 f32
    // out-proj split-K partials reuse dead regions:
    //   kslice0: ws+0        (29.36 MB, over hs_bf + wqkv head)
    //   kslice1: ws+29360128 (18.35 MB, rows 0..1279, over wqkv tail)
    //            ws+92274688 (11.01 MB, rows 1280..2047, over qr)

    cvt_all<<<35840, 256, 0, stream>>>(hs, Wq, Wk, Wv, Wo, hs_bf, wqkv_bf, wo_bf);
    concat_bias<<<18, 256, 0, stream>>>(bq, bk, bv, biasq);

    // QKV projection: 8x18 = 144 blocks (256^2 tile), 8-phase counted-vmcnt
    gemm_bt256<false, 1><<<144, 512, 0, stream>>>(hs_bf, wqkv_bf, biasq, qkv_buf, 4608, 3584, 4608);

    rope_pack4<<<4096, 256, 0, stream>>>(qkv_buf, cosp, sinp, qr, kr);
    v_transpose<<<dim3(32, 8), 256, 0, stream>>>(qkv_buf, vT);

    flash_attn<<<896, 256, 0, stream>>>(qr, kr, vT, qkv_buf);

    // output projection: split-K=2, 2x(8x14) = 224 blocks -> f32 partials in ws
    gemm_bt256<true, 2><<<224, 512, 0, stream>>>(qkv_buf, wo_bf, nullptr, d_ws, 3584, 3584, 3584);
    reduce_out<<<7168, 256, 0, stream>>>((const char*)d_ws, (float*)d_out);
}